// Round 6
// baseline (334.628 us; speedup 1.0000x reference)
//
#include <hip/hip_runtime.h>
#include <math.h>

#define TWO_G 19.6f   // 2*9.8, matches jnp's folded 2.0*G constant
#define NBLK  256

// ---- flag-array grid barrier state (module .bss, zero-initialized at load).
// Block bid only ever writes g_flags[bid]. Every launch executes exactly 15
// barriers, so ALL flags are equal at every kernel boundary; each block
// rebases from its own flag => reset-free, graph-replay/rocprof-replay safe.
__device__ __attribute__((aligned(256))) unsigned g_flags[NBLK];

__device__ __forceinline__ float flow_q(float th, float d, float a) {
    // matches reference association: (theta * sqrt(2*G*h)) * area
    return th * sqrtf(TWO_G * d) * a;
}

__device__ __forceinline__ float wave_sum(float v) {
#pragma unroll
    for (int o = 32; o > 0; o >>= 1) v += __shfl_xor(v, o);
    return v;
}

// uniform-index broadcast (j is wave-uniform at each use site)
__device__ __forceinline__ float lane_bcast(float v, int j) {
    return __int_as_float(__builtin_amdgcn_readlane(__float_as_int(v), j));
}

// agent-scope (device-coherent, sc1 -> MALL) ops: all cross-block data uses
// these, so the grid barrier needs NO L2 writeback/invalidate.
__device__ __forceinline__ float ld_agent(const float* p) {
    return __hip_atomic_load(p, __ATOMIC_RELAXED, __HIP_MEMORY_SCOPE_AGENT);
}
__device__ __forceinline__ void st_agent(float* p, float v) {
    __hip_atomic_store(p, v, __ATOMIC_RELAXED, __HIP_MEMORY_SCOPE_AGENT);
}
__device__ __forceinline__ unsigned ld_flag(const unsigned* p) {
    return __hip_atomic_load(p, __ATOMIC_RELAXED, __HIP_MEMORY_SCOPE_AGENT);
}
__device__ __forceinline__ void st_flag(unsigned* p, unsigned v) {
    __hip_atomic_store(p, v, __ATOMIC_RELAXED, __HIP_MEMORY_SCOPE_AGENT);
}

// async global->LDS DMA, 16B/lane: lds dest = wave-uniform base (+ lane*16 by HW)
__device__ __forceinline__ void dma16(const void* g, void* l) {
    __builtin_amdgcn_global_load_lds(
        (const __attribute__((address_space(1))) unsigned int*)g,
        (__attribute__((address_space(3))) unsigned int*)l, 16, 0, 0);
}

// Flag-array grid barrier. Arrivals = 256 independent sc1 stores (no atomic
// serialization); detection = per-block coalesced poll of all 256 flags.
// PRECONDITION: caller vmcnt-drained its partial sc1 stores before calling
// (flag-visible => partials-visible).
__device__ __forceinline__ void grid_barrier(unsigned target, int bid, int tid) {
    __syncthreads();                       // block's LDS work complete
    if (tid < 64) {                        // wave 0: arrive + poll
        if (tid == 0) st_flag(&g_flags[bid], target);
        for (;;) {
            int ok = 1;
#pragma unroll
            for (int k = 0; k < 4; ++k) {  // lane L reads flags[k*64+L]: coalesced
                unsigned f = ld_flag(&g_flags[k * 64 + tid]);
                ok &= ((int)(f - target) >= 0);   // wrap-safe; later gens count
            }
            if (__all(ok)) break;
            __builtin_amdgcn_s_sleep(1);
        }
    }
    __syncthreads();
    asm volatile("" ::: "memory");         // nothing hoists above the release
}

// ---------------- LDS-sourced serial solve (identical arithmetic/order) ---------
__device__ __forceinline__ float solve_lds(float H, float inflow, int lane,
                                           const char* buf, float* acc) {
    const float2* Sb = (const float2*)buf;          // 1024 float2 (row layout)
    const float*  Tb = (const float*)(buf + 8192);  // 1024 float

    float2 s_cur = Sb[lane];
    float  t_cur = Tb[lane];

    float h0 = lane_bcast(s_cur.x, 0);
    float a0 = lane_bcast(s_cur.y, 0);
    float t0 = lane_bcast(t_cur, 0);
    float d0 = (H + inflow) - h0;
    float q0 = (d0 > 0.0f) ? flow_q(t0, d0, a0) : 0.0f;
    float cum = q0;
    float u   = H - 0.5f * cum;
    if (lane == 0 && q0 != 0.0f) atomicAdd(&acc[0], q0);

#pragma unroll
    for (int c = 0; c < 16; ++c) {
        float2 s = s_cur;
        float  t = t_cur;
        if (c < 15) {                               // prefetch next chunk off-chain
            s_cur = Sb[(c + 1) * 64 + lane];
            t_cur = Tb[(c + 1) * 64 + lane];
        }
        unsigned long long avail = (c == 0) ? ~1ull : ~0ull;   // spigot 0 done
        unsigned long long cand  = __ballot(s.x < u) & avail;
        float qmine = 0.0f;
        while (cand) {
            int j = __builtin_ctzll(cand);
            float hj = lane_bcast(s.x, j);
            float aj = lane_bcast(s.y, j);
            float tj = lane_bcast(t, j);
            float d = u - hj;                       // > 0 by ballot
            float q = flow_q(tj, d, aj);
            cum += q;
            u = H - 0.5f * cum;
            if (lane == j) qmine = q;
            if (j >= 63) break;
            avail &= (~0ull << (j + 1));
            cand = __ballot(s.x < u) & avail;       // u decreased: subset of old
        }
        if (qmine != 0.0f) atomicAdd(&acc[c * 64 + lane], qmine);
    }
    return cum;
}

// ---- layer 0: single head bucket, 1024 spigots, one wave; q row -> P0 (agent) --
__device__ __forceinline__ void layer0_body(const float* __restrict__ H0p,
                                            const float* __restrict__ S0,
                                            const float* __restrict__ theta0,
                                            const float* __restrict__ precip,
                                            float* __restrict__ out,
                                            float* __restrict__ P0, int lane) {
    const float H  = H0p[0];
    const float pl = precip[0] * 0.0625f;        // precip / 16 (exact)
    const float2* S2 = (const float2*)S0;
    float2 sv[16]; float tv[16];
#pragma unroll
    for (int c = 0; c < 16; ++c) { sv[c] = S2[c * 64 + lane]; tv[c] = theta0[c * 64 + lane]; }

    float h0 = lane_bcast(sv[0].x, 0);
    float a0 = lane_bcast(sv[0].y, 0);
    float t0 = lane_bcast(tv[0], 0);
    float d0 = (H + pl) - h0;
    float q0 = (d0 > 0.0f) ? flow_q(t0, d0, a0) : 0.0f;
    float cum = q0;
    float u   = H - 0.5f * cum;
    if (lane == 0) st_agent(&P0[0], q0);

#pragma unroll
    for (int c = 0; c < 16; ++c) {
        int i = c * 64 + lane;
        float2 s = sv[c];
        unsigned long long avail = (c == 0) ? ~1ull : ~0ull;
        unsigned long long cand  = __ballot(s.x < u) & avail;
        float qmine = 0.0f;
        while (cand) {
            int j = __builtin_ctzll(cand);
            float hj = lane_bcast(s.x, j);
            float aj = lane_bcast(s.y, j);
            float tj = lane_bcast(tv[c], j);
            float d = u - hj;
            float q = flow_q(tj, d, aj);
            cum += q;
            u = H - 0.5f * cum;
            if (lane == j) qmine = q;
            if (j >= 63) break;
            avail &= (~0ull << (j + 1));
            cand = __ballot(s.x < u) & avail;
        }
        if (i > 0) st_agent(&P0[i], qmine);
    }
    if (lane == 0) out[0] = (H - cum) + pl;      // H0_new
}

// ---- the whole cascade: 1 regular kernel, 256 blocks (1/CU), flag barrier -----
__global__ __launch_bounds__(256, 1)
void cascade_kernel(const float* __restrict__ H0p, const float* __restrict__ Hmid,
                    const float* __restrict__ Hlast, const float* __restrict__ S0,
                    const float* __restrict__ Smid, const float* __restrict__ Slast,
                    const float* __restrict__ th0, const float* __restrict__ thmid,
                    const float* __restrict__ thlast, const float* __restrict__ precip,
                    float* __restrict__ out, float* __restrict__ PA, float* __restrict__ PB)
{
    __shared__ float acc[1024];                     // block-level q accumulator
    __shared__ __align__(16) char sbuf[4][12288];   // per-wave: S row 8 KB + theta 4 KB

    const int tid  = threadIdx.x;
    const int lane = tid & 63;
    const int w    = tid >> 6;
    const int bid  = blockIdx.x;
    const int b    = bid * 4 + w;               // bucket<->wave mapping (unchanged)

    // rebase from OWN flag (only this block ever writes it; all flags equal at
    // launch boundaries because every launch passes exactly 15 barriers)
    const unsigned base = ld_flag(&g_flags[bid]);

#pragma unroll
    for (int r = 0; r < 4; ++r) acc[r * 256 + tid] = 0.0f;

    const float pb = precip[0] * (0.0625f / 1024.0f);   // exact: 2^-14 * precip

    // ---- pre-loop: DMA-stage mid layer 0 for this wave's bucket ----
    {
        char* dst = sbuf[w];
        const char* gS = (const char*)Smid + (size_t)b * 8192;
        const char* gT = (const char*)thmid + (size_t)b * 4096;
#pragma unroll
        for (int i = 0; i < 8; ++i) dma16(gS + i * 1024 + lane * 16, dst + i * 1024);
#pragma unroll
        for (int i = 0; i < 4; ++i) dma16(gT + i * 1024 + lane * 16, dst + 8192 + i * 1024);
    }
    // head bucket runs on block 0 / wave 0 while all staging DMAs fly
    if (bid == 0 && w == 0)
        layer0_body(H0p, S0, th0, precip, out, PA, lane);
    asm volatile("s_waitcnt vmcnt(0)" ::: "memory");   // P0 stores + DMA drained
    grid_barrier(base + 1u, bid, tid);

#pragma unroll 1
    for (int l = 0; l < 14; ++l) {
        const float* Pin = (l & 1) ? PB : PA;
        float*       Pou = (l & 1) ? PA : PB;

        // 1) inflow gather (agent loads -> MALL, always coherent) + reduce
        float part = 0.0f;
        if (l == 0) {
            if (lane == 0) part = ld_agent(&Pin[b]);    // layer0 wrote one row
        } else {
#pragma unroll
            for (int k = 0; k < 4; ++k)
                part += ld_agent(&Pin[(size_t)(k * 64 + lane) * 1024 + b]);
        }
        const float H      = Hmid[(size_t)l * 1024 + b];
        const float inflow = pb + wave_sum(part);

        // 2) serial solve from this wave's LDS buffer (DMA'd last iteration)
        const float cum = solve_lds(H, inflow, lane, sbuf[w], acc);
        if (lane == 0) out[1 + (size_t)l * 1024 + b] = (H - cum) + inflow;

        __syncthreads();                        // all waves' acc atomics complete

        // 3) dense partial row -> global (agent stores), re-arm acc
#pragma unroll
        for (int r = 0; r < 4; ++r) {
            const int idx = r * 256 + tid;
            st_agent(&Pou[(size_t)bid * 1024 + idx], acc[idx]);
            acc[idx] = 0.0f;
        }
        asm volatile("" ::: "memory");

        // 4) issue next layer's staging DMA, then vmcnt(12): the 4 partial
        //    stores (older, in-order retirement) are drained -- the flag store
        //    after this is only visible with partials visible -- while the 12
        //    DMAs stay in flight across the barrier spin (T4-style).
        if (l < 13) {
            char* dst = sbuf[w];
            const char* gS = (const char*)Smid + (size_t)(l + 1) * 8388608 + (size_t)b * 8192;
            const char* gT = (const char*)thmid + (size_t)(l + 1) * 4194304 + (size_t)b * 4096;
#pragma unroll
            for (int i = 0; i < 8; ++i) dma16(gS + i * 1024 + lane * 16, dst + i * 1024);
#pragma unroll
            for (int i = 0; i < 4; ++i) dma16(gT + i * 1024 + lane * 16, dst + 8192 + i * 1024);
            asm volatile("s_waitcnt vmcnt(12)" ::: "memory");
        } else {
            asm volatile("s_waitcnt vmcnt(0)" ::: "memory");
        }

        grid_barrier(base + 2u + (unsigned)l, bid, tid);   // partials published
        asm volatile("s_waitcnt vmcnt(0)" ::: "memory");   // DMA landed in LDS
    }

    // ---- last layer: 1 spigot per bucket (l=13 wrote PA) ----
    {
        float part = 0.0f;
#pragma unroll
        for (int k = 0; k < 4; ++k)
            part += ld_agent(&PA[(size_t)(k * 64 + lane) * 1024 + b]);
        const float inflow = pb + wave_sum(part);
        if (lane == 0) {
            const float  Hv = Hlast[b];
            const float2 s  = ((const float2*)Slast)[b];
            const float  d  = (Hv + inflow) - s.x;
            const float  q  = (d > 0.0f) ? flow_q(thlast[b], d, s.y) : 0.0f;
            out[1 + 14 * 1024 + b]        = (Hv - q) + inflow;   // H_last_new
            out[1 + 14 * 1024 + 1024 + b] = q;                   // q_last
        }
    }
}

extern "C" void kernel_launch(void* const* d_in, const int* in_sizes, int n_in,
                              void* d_out, int out_size, void* d_ws, size_t ws_size,
                              hipStream_t stream)
{
    (void)in_sizes; (void)n_in; (void)out_size; (void)ws_size;
    const float* H0     = (const float*)d_in[0];
    const float* Hmid   = (const float*)d_in[1];
    const float* Hlast  = (const float*)d_in[2];
    const float* S0     = (const float*)d_in[3];
    const float* Smid   = (const float*)d_in[4];
    const float* Slast  = (const float*)d_in[5];
    const float* th0    = (const float*)d_in[6];
    const float* thmid  = (const float*)d_in[7];
    const float* thlast = (const float*)d_in[8];
    const float* precip = (const float*)d_in[9];
    float* out = (float*)d_out;
    float* PA  = (float*)d_ws;                 // 256 x 1024 partials (ping)
    float* PB  = PA + (size_t)256 * 1024;      // pong

    // Regular launch: 256 blocks x 53 KB LDS on 256 CUs are trivially
    // co-resident, so no cooperative-launch machinery is needed.
    cascade_kernel<<<dim3(256), dim3(256), 0, stream>>>(
        H0, Hmid, Hlast, S0, Smid, Slast, th0, thmid, thlast, precip, out, PA, PB);
}

// Round 7
// 328.796 us; speedup vs baseline: 1.0177x; 1.0177x over previous
//
#include <hip/hip_runtime.h>
#include <math.h>

#define TWO_G 19.6f   // 2*9.8, matches jnp's folded 2.0*G constant
#define NBLK  256

typedef __attribute__((ext_vector_type(4))) float f32x4;

// ---- flag-array grid barrier state (module .bss, zero-initialized at load).
// Block bid only ever writes g_flags[bid]. Every launch executes exactly 15
// barriers, so ALL flags are equal at every kernel boundary; each block
// rebases from its own flag => reset-free, graph-replay/rocprof-replay safe.
__device__ __attribute__((aligned(256))) unsigned g_flags[NBLK];

__device__ __forceinline__ float flow_q(float th, float d, float a) {
    // reference association: (theta * sqrt(2*G*h)) * area.
    // RAW v_sqrt_f32 (~1ulp) instead of IEEE-correct sqrtf: removes the ~6-op
    // correctly-rounded fixup from the serial chain (the round-7 gamble; if
    // absmax exceeds tolerance, revert this one line to sqrtf).
    return th * __builtin_amdgcn_sqrtf(TWO_G * d) * a;
}

__device__ __forceinline__ float wave_sum(float v) {
#pragma unroll
    for (int o = 32; o > 0; o >>= 1) v += __shfl_xor(v, o);
    return v;
}

// uniform-index broadcast (j is wave-uniform at each use site)
__device__ __forceinline__ float lane_bcast(float v, int j) {
    return __int_as_float(__builtin_amdgcn_readlane(__float_as_int(v), j));
}

// agent-scope (device-coherent, sc1 -> MALL) ops for all cross-block data
__device__ __forceinline__ float ld_agent(const float* p) {
    return __hip_atomic_load(p, __ATOMIC_RELAXED, __HIP_MEMORY_SCOPE_AGENT);
}
__device__ __forceinline__ void st_agent(float* p, float v) {
    __hip_atomic_store(p, v, __ATOMIC_RELAXED, __HIP_MEMORY_SCOPE_AGENT);
}
__device__ __forceinline__ unsigned ld_flag(const unsigned* p) {
    return __hip_atomic_load(p, __ATOMIC_RELAXED, __HIP_MEMORY_SCOPE_AGENT);
}
__device__ __forceinline__ void st_flag(unsigned* p, unsigned v) {
    __hip_atomic_store(p, v, __ATOMIC_RELAXED, __HIP_MEMORY_SCOPE_AGENT);
}

// 16B agent-coherent load (sc1 = same coherence level ld_agent emits), with
// embedded wait so the result is valid (compiler can't track asm loads).
__device__ __forceinline__ f32x4 ld_agent4(const float* p) {
    f32x4 r;
    asm volatile("global_load_dwordx4 %0, %1, off sc1\n\t"
                 "s_waitcnt vmcnt(0)"
                 : "=v"(r) : "v"(p) : "memory");
    return r;
}

// async global->LDS DMA, 16B/lane: lds dest = wave-uniform base (+ lane*16 by HW)
__device__ __forceinline__ void dma16(const void* g, void* l) {
    __builtin_amdgcn_global_load_lds(
        (const __attribute__((address_space(1))) unsigned int*)g,
        (__attribute__((address_space(3))) unsigned int*)l, 16, 0, 0);
}

// Flag-array grid barrier (round-6, kept): arrivals = independent sc1 stores;
// detection = per-block coalesced poll. PRECONDITION: caller vmcnt-drained its
// partial sc1 stores before calling (flag-visible => partials-visible).
__device__ __forceinline__ void grid_barrier(unsigned target, int bid, int tid) {
    __syncthreads();                       // block's LDS work complete
    if (tid < 64) {                        // wave 0: arrive + poll
        if (tid == 0) st_flag(&g_flags[bid], target);
        for (;;) {
            int ok = 1;
#pragma unroll
            for (int k = 0; k < 4; ++k) {  // lane L reads flags[k*64+L]: coalesced
                unsigned f = ld_flag(&g_flags[k * 64 + tid]);
                ok &= ((int)(f - target) >= 0);   // wrap-safe; later gens count
            }
            if (__all(ok)) break;
            __builtin_amdgcn_s_sleep(1);
        }
    }
    __syncthreads();
    asm volatile("" ::: "memory");         // nothing hoists above the release
}

// ---------------- LDS-sourced serial solve --------------------------------------
// Branchless candidate-mask update: (~1ull)<<j == ~0ull<<(j+1) for j<63 and == 0
// for j==63 (defined behavior), so the j>=63 break disappears from the loop.
__device__ __forceinline__ float solve_lds(float H, float inflow, int lane,
                                           const char* buf, float* acc) {
    const float2* Sb = (const float2*)buf;          // 1024 float2 (row layout)
    const float*  Tb = (const float*)(buf + 8192);  // 1024 float

    float2 s_cur = Sb[lane];
    float  t_cur = Tb[lane];

    float h0 = lane_bcast(s_cur.x, 0);
    float a0 = lane_bcast(s_cur.y, 0);
    float t0 = lane_bcast(t_cur, 0);
    float d0 = (H + inflow) - h0;
    float q0 = (d0 > 0.0f) ? flow_q(t0, d0, a0) : 0.0f;
    float cum = q0;
    float u   = H - 0.5f * cum;
    if (lane == 0 && q0 != 0.0f) atomicAdd(&acc[0], q0);

#pragma unroll
    for (int c = 0; c < 16; ++c) {
        float2 s = s_cur;
        float  t = t_cur;
        if (c < 15) {                               // prefetch next chunk off-chain
            s_cur = Sb[(c + 1) * 64 + lane];
            t_cur = Tb[(c + 1) * 64 + lane];
        }
        unsigned long long avail = (c == 0) ? ~1ull : ~0ull;   // spigot 0 done
        unsigned long long cand  = __ballot(s.x < u) & avail;
        float qmine = 0.0f;
        while (cand) {
            int j = __builtin_ctzll(cand);
            float hj = lane_bcast(s.x, j);
            float aj = lane_bcast(s.y, j);
            float tj = lane_bcast(t, j);
            float d = u - hj;                       // > 0 by ballot
            float q = flow_q(tj, d, aj);
            cum += q;
            u = H - 0.5f * cum;
            if (lane == j) qmine = q;
            avail &= (~1ull) << j;                  // clears bits <= j; 0 at j==63
            cand = __ballot(s.x < u) & avail;       // u decreased: subset of old
        }
        if (qmine != 0.0f) atomicAdd(&acc[c * 64 + lane], qmine);
    }
    return cum;
}

// ---- layer 0: single head bucket, 1024 spigots, one wave; q row -> P0 (agent) --
__device__ __forceinline__ void layer0_body(const float* __restrict__ H0p,
                                            const float* __restrict__ S0,
                                            const float* __restrict__ theta0,
                                            const float* __restrict__ precip,
                                            float* __restrict__ out,
                                            float* __restrict__ P0, int lane) {
    const float H  = H0p[0];
    const float pl = precip[0] * 0.0625f;        // precip / 16 (exact)
    const float2* S2 = (const float2*)S0;
    float2 sv[16]; float tv[16];
#pragma unroll
    for (int c = 0; c < 16; ++c) { sv[c] = S2[c * 64 + lane]; tv[c] = theta0[c * 64 + lane]; }

    float h0 = lane_bcast(sv[0].x, 0);
    float a0 = lane_bcast(sv[0].y, 0);
    float t0 = lane_bcast(tv[0], 0);
    float d0 = (H + pl) - h0;
    float q0 = (d0 > 0.0f) ? flow_q(t0, d0, a0) : 0.0f;
    float cum = q0;
    float u   = H - 0.5f * cum;
    if (lane == 0) st_agent(&P0[0], q0);

#pragma unroll
    for (int c = 0; c < 16; ++c) {
        int i = c * 64 + lane;
        float2 s = sv[c];
        unsigned long long avail = (c == 0) ? ~1ull : ~0ull;
        unsigned long long cand  = __ballot(s.x < u) & avail;
        float qmine = 0.0f;
        while (cand) {
            int j = __builtin_ctzll(cand);
            float hj = lane_bcast(s.x, j);
            float aj = lane_bcast(s.y, j);
            float tj = lane_bcast(tv[c], j);
            float d = u - hj;
            float q = flow_q(tj, d, aj);
            cum += q;
            u = H - 0.5f * cum;
            if (lane == j) qmine = q;
            avail &= (~1ull) << j;
            cand = __ballot(s.x < u) & avail;
        }
        if (i > 0) st_agent(&P0[i], qmine);
    }
    if (lane == 0) out[0] = (H - cum) + pl;      // H0_new
}

// ---- the whole cascade: 1 regular kernel, 256 blocks (1/CU), flag barrier -----
__global__ __launch_bounds__(256, 1)
void cascade_kernel(const float* __restrict__ H0p, const float* __restrict__ Hmid,
                    const float* __restrict__ Hlast, const float* __restrict__ S0,
                    const float* __restrict__ Smid, const float* __restrict__ Slast,
                    const float* __restrict__ th0, const float* __restrict__ thmid,
                    const float* __restrict__ thlast, const float* __restrict__ precip,
                    float* __restrict__ out, float* __restrict__ PA, float* __restrict__ PB)
{
    __shared__ float acc[1024];                     // block-level q accumulator
    __shared__ __align__(16) char sbuf[4][12288];   // per-wave: S row 8 KB + theta 4 KB
    __shared__ float xpose[256][5];                 // gather transpose (pad 5: no conflicts)

    const int tid  = threadIdx.x;
    const int lane = tid & 63;
    const int w    = tid >> 6;
    const int bid  = blockIdx.x;
    const int b    = bid * 4 + w;               // bucket<->wave mapping (unchanged)

    // rebase from OWN flag (only this block ever writes it; all flags equal at
    // launch boundaries because every launch passes exactly 15 barriers)
    const unsigned base = ld_flag(&g_flags[bid]);

#pragma unroll
    for (int r = 0; r < 4; ++r) acc[r * 256 + tid] = 0.0f;

    const float pb = precip[0] * (0.0625f / 1024.0f);   // exact: 2^-14 * precip

    // ---- pre-loop: DMA-stage mid layer 0 for this wave's bucket ----
    {
        char* dst = sbuf[w];
        const char* gS = (const char*)Smid + (size_t)b * 8192;
        const char* gT = (const char*)thmid + (size_t)b * 4096;
#pragma unroll
        for (int i = 0; i < 8; ++i) dma16(gS + i * 1024 + lane * 16, dst + i * 1024);
#pragma unroll
        for (int i = 0; i < 4; ++i) dma16(gT + i * 1024 + lane * 16, dst + 8192 + i * 1024);
    }
    // head bucket runs on block 0 / wave 0 while all staging DMAs fly
    if (bid == 0 && w == 0)
        layer0_body(H0p, S0, th0, precip, out, PA, lane);
    asm volatile("s_waitcnt vmcnt(0)" ::: "memory");   // P0 stores + DMA drained
    grid_barrier(base + 1u, bid, tid);

#pragma unroll 1
    for (int l = 0; l < 14; ++l) {
        const float* Pin = (l & 1) ? PB : PA;
        float*       Pou = (l & 1) ? PA : PB;

        // 1) inflow gather: block-cooperative row-chunk load + LDS transpose.
        //    Thread t loads row t's 4-col (16 B) chunk for this block's buckets;
        //    per-wave sum order (k = lane, lane+64, lane+128, lane+192) is
        //    bit-identical to the previous column-strided gather.
        float part = 0.0f;
        if (l == 0) {
            if (lane == 0) part = ld_agent(&Pin[b]);    // layer0 wrote one row
        } else {
            f32x4 v = ld_agent4(Pin + (size_t)tid * 1024 + bid * 4);
            xpose[tid][0] = v.x; xpose[tid][1] = v.y;
            xpose[tid][2] = v.z; xpose[tid][3] = v.w;
            __syncthreads();
#pragma unroll
            for (int r = 0; r < 4; ++r) part += xpose[r * 64 + lane][w];
        }
        const float H      = Hmid[(size_t)l * 1024 + b];
        const float inflow = pb + wave_sum(part);

        // 2) serial solve from this wave's LDS buffer (DMA'd last iteration;
        //    drained by the ld_agent4 vmcnt(0) / the post-barrier drain below)
        const float cum = solve_lds(H, inflow, lane, sbuf[w], acc);
        if (lane == 0) out[1 + (size_t)l * 1024 + b] = (H - cum) + inflow;

        __syncthreads();                        // all waves' acc atomics complete

        // 3) dense partial row -> global (agent stores), re-arm acc
#pragma unroll
        for (int r = 0; r < 4; ++r) {
            const int idx = r * 256 + tid;
            st_agent(&Pou[(size_t)bid * 1024 + idx], acc[idx]);
            acc[idx] = 0.0f;
        }
        asm volatile("" ::: "memory");

        // 4) issue next layer's staging DMA, then vmcnt(12): the out-store + 4
        //    partial stores (older, in-order retirement) are drained -- so the
        //    flag store is only visible with partials visible -- while the 12
        //    DMAs stay in flight across the barrier spin (T4-style).
        if (l < 13) {
            char* dst = sbuf[w];
            const char* gS = (const char*)Smid + (size_t)(l + 1) * 8388608 + (size_t)b * 8192;
            const char* gT = (const char*)thmid + (size_t)(l + 1) * 4194304 + (size_t)b * 4096;
#pragma unroll
            for (int i = 0; i < 8; ++i) dma16(gS + i * 1024 + lane * 16, dst + i * 1024);
#pragma unroll
            for (int i = 0; i < 4; ++i) dma16(gT + i * 1024 + lane * 16, dst + 8192 + i * 1024);
            asm volatile("s_waitcnt vmcnt(12)" ::: "memory");
        } else {
            asm volatile("s_waitcnt vmcnt(0)" ::: "memory");
        }

        grid_barrier(base + 2u + (unsigned)l, bid, tid);   // partials published
        asm volatile("s_waitcnt vmcnt(0)" ::: "memory");   // DMA landed in LDS
    }

    // ---- last layer: 1 spigot per bucket (l=13 wrote PA) ----
    {
        f32x4 v = ld_agent4(PA + (size_t)tid * 1024 + bid * 4);
        xpose[tid][0] = v.x; xpose[tid][1] = v.y;
        xpose[tid][2] = v.z; xpose[tid][3] = v.w;
        __syncthreads();
        float part = 0.0f;
#pragma unroll
        for (int r = 0; r < 4; ++r) part += xpose[r * 64 + lane][w];
        const float inflow = pb + wave_sum(part);
        if (lane == 0) {
            const float  Hv = Hlast[b];
            const float2 s  = ((const float2*)Slast)[b];
            const float  d  = (Hv + inflow) - s.x;
            const float  q  = (d > 0.0f) ? flow_q(thlast[b], d, s.y) : 0.0f;
            out[1 + 14 * 1024 + b]        = (Hv - q) + inflow;   // H_last_new
            out[1 + 14 * 1024 + 1024 + b] = q;                   // q_last
        }
    }
}

extern "C" void kernel_launch(void* const* d_in, const int* in_sizes, int n_in,
                              void* d_out, int out_size, void* d_ws, size_t ws_size,
                              hipStream_t stream)
{
    (void)in_sizes; (void)n_in; (void)out_size; (void)ws_size;
    const float* H0     = (const float*)d_in[0];
    const float* Hmid   = (const float*)d_in[1];
    const float* Hlast  = (const float*)d_in[2];
    const float* S0     = (const float*)d_in[3];
    const float* Smid   = (const float*)d_in[4];
    const float* Slast  = (const float*)d_in[5];
    const float* th0    = (const float*)d_in[6];
    const float* thmid  = (const float*)d_in[7];
    const float* thlast = (const float*)d_in[8];
    const float* precip = (const float*)d_in[9];
    float* out = (float*)d_out;
    float* PA  = (float*)d_ws;                 // 256 x 1024 partials (ping)
    float* PB  = PA + (size_t)256 * 1024;      // pong

    cascade_kernel<<<dim3(256), dim3(256), 0, stream>>>(
        H0, Hmid, Hlast, S0, Smid, Slast, th0, thmid, thlast, precip, out, PA, PB);
}